// Round 2
// baseline (1031.456 us; speedup 1.0000x reference)
//
#include <hip/hip_runtime.h>
#include <hip/hip_bf16.h>

typedef __attribute__((ext_vector_type(8))) short short8;
typedef __attribute__((ext_vector_type(4))) short short4v;
typedef __attribute__((ext_vector_type(4))) float floatx4;
typedef __attribute__((ext_vector_type(4))) unsigned int uint4v;

using bf16 = __hip_bfloat16;

#define DEVI __device__ __forceinline__

// ---------------- workspace layout (bytes) ----------------
static constexpr size_t OFF_SCORE  = 0;                        // 128*128 f32
static constexpr size_t OFF_XCC    = 65536;                    // 8 groups * 32 slots u32 (+pad)
static constexpr size_t OFF_CPUB   = OFF_XCC + 4096;           // 2 x (128*512 u64) epoch-tagged C
static constexpr size_t ZERO_BYTES = OFF_CPUB + 524288;        // score + xcc + Cpub buf0 (epoch0 == C0=0)
static constexpr size_t OFF_G      = OFF_CPUB   + 1048576;     // 128*128 f32
static constexpr size_t OFF_BIASR  = OFF_G      + 65536;       // 1024 f32
static constexpr size_t OFF_CFIN   = OFF_BIASR  + 4096;        // 128*1024 f32
static constexpr size_t OFF_CONCAT = OFF_CFIN   + 524288;      // 128*3072 bf16
static constexpr size_t OFF_FACTS  = OFF_CONCAT + 786432;      // 16M bf16
static constexpr size_t OFF_WZ1    = OFF_FACTS  + 33554432ull; // 1024*4096 bf16
static constexpr size_t OFF_WRW    = OFF_WZ1    + 8388608ull;  // 2048*1024 bf16
static constexpr size_t OFF_URU    = OFF_WRW    + 4194304ull;  // 2048*1024 bf16
static constexpr size_t OFF_WM     = OFF_URU    + 4194304ull;  // 1024*3072 bf16
static constexpr size_t OFF_P      = OFF_WM     + 6291456ull;  // 128*128*2048 bf16

DEVI float sigm_f(float x){ return 1.f/(1.f + __expf(-x)); }
DEVI float tanh_f(float x){ float e = __expf(2.f*x); return 1.f - 2.f/(e + 1.f); }

// ---- coherence-tiered access helpers ----
// slow tier (cross-XCD): sc0 sc1 -> die-level coherent point (R6-proven)
// fast tier (same-XCD):  plain store (lands in this XCD's L2) + sc0 load
//                        (bypasses L1, served by the same L2) — L2 RTT ~200cyc
DEVI uint4v ld_cg_u128(const uint4v* p){
  uint4v r;
  asm volatile("global_load_dwordx4 %0, %1, off sc0 sc1" : "=v"(r) : "v"(p) : "memory");
  return r;
}
DEVI uint4v ld_l2_u128(const uint4v* p){
  uint4v r;
  asm volatile("global_load_dwordx4 %0, %1, off sc0" : "=v"(r) : "v"(p) : "memory");
  return r;
}
DEVI void st_cg_u64(unsigned long long* p, unsigned long long v){
  asm volatile("global_store_dwordx2 %0, %1, off sc0 sc1" : : "v"(p), "v"(v) : "memory");
}
DEVI void st_l2_u64(unsigned long long* p, unsigned long long v){
  asm volatile("global_store_dwordx2 %0, %1, off" : : "v"(p), "v"(v) : "memory");
}
DEVI void waitcnt_vm0(){ asm volatile("s_waitcnt vmcnt(0)" ::: "memory"); }

// ---------------- small utility kernels ----------------
__global__ void cast_f32_bf16(const float* __restrict__ src, bf16* __restrict__ dst, int n){
  int i = (blockIdx.x*256 + threadIdx.x)*4;
  if (i >= n) return;
  float4 v = *(const float4*)(src + i);
  union { bf16 h[4]; short4v s; } u;
  u.h[0] = __float2bfloat16(v.x); u.h[1] = __float2bfloat16(v.y);
  u.h[2] = __float2bfloat16(v.z); u.h[3] = __float2bfloat16(v.w);
  *(short4v*)(dst + i) = u.s;
}

__global__ void add_bias_k(const float* __restrict__ a, const float* __restrict__ b, float* __restrict__ o){
  int i = blockIdx.x*256 + threadIdx.x;
  if (i < 1024) o[i] = a[i] + b[i];
}

__global__ void softmax128(const float* __restrict__ score, float* __restrict__ G){
  int b = blockIdx.x, t = threadIdx.x;
  int lane = t & 63, wv = t >> 6;
  float v = score[b*128 + t];
  float mx = v;
  #pragma unroll
  for (int m = 1; m < 64; m <<= 1) mx = fmaxf(mx, __shfl_xor(mx, m));
  __shared__ float r1[2], r2[2];
  if (lane == 0) r1[wv] = mx;
  __syncthreads();
  mx = fmaxf(r1[0], r1[1]);
  float e = __expf(v - mx);
  float sm = e;
  #pragma unroll
  for (int m = 1; m < 64; m <<= 1) sm += __shfl_xor(sm, m);
  if (lane == 0) r2[wv] = sm;
  __syncthreads();
  sm = r2[0] + r2[1];
  G[b*128 + t] = e / sm;
}

__global__ void build_concat(const float* __restrict__ prevM, const float* __restrict__ Cfin,
                             const float* __restrict__ q, bf16* __restrict__ out){
  int i = (blockIdx.x*256 + threadIdx.x)*4;   // n = 128*3072
  if (i >= 128*3072) return;
  int b = i / 3072, k = i % 3072;
  const float* src = (k < 1024) ? (prevM + b*1024 + k)
                   : (k < 2048) ? (Cfin + b*1024 + (k-1024))
                                : (q    + b*1024 + (k-2048));
  float4 v = *(const float4*)src;
  union { bf16 h[4]; short4v s; } u;
  u.h[0] = __float2bfloat16(v.x); u.h[1] = __float2bfloat16(v.y);
  u.h[2] = __float2bfloat16(v.z); u.h[3] = __float2bfloat16(v.w);
  *(short4v*)(out + i) = u.s;
}

// ---------------- gate GEMM (R2-proven form): z on-the-fly, fused epilogue ----------------
__global__ __launch_bounds__(256, 2) void gate_gemm(
    const float* __restrict__ facts, const float* __restrict__ q,
    const float* __restrict__ pm, const bf16* __restrict__ Wz1b,
    const float* __restrict__ bz1, const float* __restrict__ wz2,
    float* __restrict__ score)
{
  constexpr int TS = 80;
  __shared__ bf16 As[128*TS];
  __shared__ bf16 Bs[128*TS];
  __shared__ float qs[1024];
  __shared__ float ms[1024];
  int tid = threadIdx.x;
  int b  = blockIdx.y;
  int n0 = blockIdx.x * 128;
  int w = tid >> 6, lane = tid & 63;
  int wm = w >> 1, wn = w & 1;
  int quad = lane >> 4, col = lane & 15;

  for (int i = tid; i < 1024; i += 256){ qs[i] = q[b*1024 + i]; ms[i] = pm[b*1024 + i]; }
  __syncthreads();

  floatx4 acc[4][4];
  #pragma unroll
  for (int a = 0; a < 4; ++a)
    #pragma unroll
    for (int c = 0; c < 4; ++c) acc[a][c] = (floatx4){0.f,0.f,0.f,0.f};

  for (int it = 0; it < 64; ++it){
    int k0 = it * 64;
    int qd = k0 >> 10;
    int kk0 = k0 & 1023;
    #pragma unroll
    for (int i = 0; i < 4; ++i){
      int c = tid + i*256;
      int r = c >> 3, cc = c & 7;
      int kk = kk0 + cc*8;
      const float* fp = facts + (size_t)(b*128 + r)*1024 + kk;
      float f[8], aux[8];
      *(float4*)(f)   = *(const float4*)(fp);
      *(float4*)(f+4) = *(const float4*)(fp + 4);
      const float* av = (qd == 0 || qd == 2) ? qs : ms;
      *(float4*)(aux)   = *(const float4*)(av + kk);
      *(float4*)(aux+4) = *(const float4*)(av + kk + 4);
      union { bf16 h[8]; short8 s8; } u;
      if (qd < 2){
        #pragma unroll
        for (int j = 0; j < 8; ++j) u.h[j] = __float2bfloat16(f[j]*aux[j]);
      } else {
        #pragma unroll
        for (int j = 0; j < 8; ++j) u.h[j] = __float2bfloat16(fabsf(f[j]-aux[j]));
      }
      *(short8*)&As[r*TS + cc*8] = u.s8;
    }
    #pragma unroll
    for (int i = 0; i < 4; ++i){
      int c = tid + i*256;
      int r = c >> 3, cc = c & 7;
      *(uint4v*)&Bs[r*TS + cc*8] = *(const uint4v*)(Wz1b + (size_t)(n0 + r)*4096 + k0 + cc*8);
    }
    __syncthreads();
    #pragma unroll
    for (int kt = 0; kt < 2; ++kt){
      short8 af[4], bfv[4];
      #pragma unroll
      for (int mt = 0; mt < 4; ++mt)
        af[mt] = *(const short8*)&As[(wm*64 + mt*16 + col)*TS + kt*32 + quad*8];
      #pragma unroll
      for (int nt = 0; nt < 4; ++nt)
        bfv[nt] = *(const short8*)&Bs[(wn*64 + nt*16 + col)*TS + kt*32 + quad*8];
      #pragma unroll
      for (int mt = 0; mt < 4; ++mt)
        #pragma unroll
        for (int nt = 0; nt < 4; ++nt)
          acc[mt][nt] = __builtin_amdgcn_mfma_f32_16x16x32_bf16(af[mt], bfv[nt], acc[mt][nt], 0,0,0);
    }
    __syncthreads();
  }
  #pragma unroll
  for (int mt = 0; mt < 4; ++mt){
    float part[4] = {0.f,0.f,0.f,0.f};
    #pragma unroll
    for (int nt = 0; nt < 4; ++nt){
      int n = n0 + wn*64 + nt*16 + col;
      float b1 = bz1[n], w2 = wz2[n];
      #pragma unroll
      for (int rr = 0; rr < 4; ++rr)
        part[rr] += tanh_f(acc[mt][nt][rr] + b1) * w2;
    }
    #pragma unroll
    for (int rr = 0; rr < 4; ++rr){
      float p = part[rr];
      p += __shfl_xor(p, 1); p += __shfl_xor(p, 2);
      p += __shfl_xor(p, 4); p += __shfl_xor(p, 8);
      if (col == 0)
        atomicAdd(&score[b*128 + wm*64 + mt*16 + quad*4 + rr], p);
    }
  }
}

// ---------------- generic 128x128 bf16 GEMM (B^T layout, R2-proven form) ----------------
template<int MODE>
__global__ __launch_bounds__(256, 2) void gemm_bt(
    const bf16* __restrict__ A, const bf16* __restrict__ Bm, int K,
    bf16* __restrict__ Pout, const float* __restrict__ bias, float* __restrict__ out)
{
  constexpr int TS = 80;
  __shared__ bf16 As[128*TS];
  __shared__ bf16 Bs[128*TS];
  int tid = threadIdx.x;
  int m0 = blockIdx.y * 128, n0 = blockIdx.x * 128;
  int w = tid >> 6, lane = tid & 63;
  int wm = w >> 1, wn = w & 1;
  int quad = lane >> 4, col = lane & 15;

  floatx4 acc[4][4];
  #pragma unroll
  for (int a = 0; a < 4; ++a)
    #pragma unroll
    for (int c = 0; c < 4; ++c) acc[a][c] = (floatx4){0.f,0.f,0.f,0.f};

  int nkb = K >> 6;
  for (int it = 0; it < nkb; ++it){
    int k0 = it * 64;
    #pragma unroll
    for (int i = 0; i < 4; ++i){
      int c = tid + i*256;
      int r = c >> 3, cc = c & 7;
      *(uint4v*)&As[r*TS + cc*8] = *(const uint4v*)(A  + (size_t)(m0 + r)*K + k0 + cc*8);
      *(uint4v*)&Bs[r*TS + cc*8] = *(const uint4v*)(Bm + (size_t)(n0 + r)*K + k0 + cc*8);
    }
    __syncthreads();
    #pragma unroll
    for (int kt = 0; kt < 2; ++kt){
      short8 af[4], bfv[4];
      #pragma unroll
      for (int mt = 0; mt < 4; ++mt)
        af[mt] = *(const short8*)&As[(wm*64 + mt*16 + col)*TS + kt*32 + quad*8];
      #pragma unroll
      for (int nt = 0; nt < 4; ++nt)
        bfv[nt] = *(const short8*)&Bs[(wn*64 + nt*16 + col)*TS + kt*32 + quad*8];
      #pragma unroll
      for (int mt = 0; mt < 4; ++mt)
        #pragma unroll
        for (int nt = 0; nt < 4; ++nt)
          acc[mt][nt] = __builtin_amdgcn_mfma_f32_16x16x32_bf16(af[mt], bfv[nt], acc[mt][nt], 0,0,0);
    }
    __syncthreads();
  }
  #pragma unroll
  for (int mt = 0; mt < 4; ++mt)
    #pragma unroll
    for (int nt = 0; nt < 4; ++nt)
      #pragma unroll
      for (int rr = 0; rr < 4; ++rr){
        int m = m0 + wm*64 + mt*16 + quad*4 + rr;
        int n = n0 + wn*64 + nt*16 + col;
        float v = acc[mt][nt][rr];
        if (MODE == 0){
          Pout[((size_t)(m & 127)*128 + (m >> 7))*2048 + n] = __float2bfloat16(v);
        } else {
          out[(size_t)m*1024 + n] = fmaxf(v + bias[n], 0.f);
        }
      }
}

// ---------------- the sequential scan ----------------
// 256 blocks; group g = blockIdx&7 (XCD-affine under measured round-robin
// dispatch), col block nb = blockIdx>>3. One-time runtime XCD discovery
// (s_getreg XCC_ID builtin + agent-atomic exchange) picks the coherence tier:
// all-same-XCD group -> fast (plain store / sc0 load, XCD-L2 coherent);
// otherwise -> slow (sc0 sc1, R6-proven). Protocol itself is R6's passing
// epoch-tagged data-poll in both tiers (correct under ANY mapping).
__global__ __launch_bounds__(256, 1) void scan_kernel(
    const bf16* __restrict__ UrU, const bf16* __restrict__ P,
    const float* __restrict__ G, const float* __restrict__ bias_r,
    const float* __restrict__ bw, const float* __restrict__ bu,
    unsigned long long* __restrict__ Cpub, float* __restrict__ Cfinal,
    unsigned int* __restrict__ xcc_slots)
{
  constexpr int CS = 1040;               // padded LDS stride (bf16), 16B-aligned
  __shared__ bf16 Cs[16*CS];
  __shared__ float Qex[2*16*32];         // [matrix][batch][col]
  int tid = threadIdx.x;
  int g  = blockIdx.x & 7;               // XCD-affine batch group 0..7
  int nb = blockIdx.x >> 3;              // column block 0..31
  int b0 = g * 16, j0 = nb * 32;
  int w = tid >> 6, lane = tid & 63;
  int quad = lane >> 4, col = lane & 15;

  // ---- one-time XCD discovery; all blocks co-resident (scan requires it) ----
  // hwreg encoding: id=20 (HW_REG_XCC_ID, measured m09), offset=0, size=32.
  unsigned int my_tag = __builtin_amdgcn_s_getreg(20 | (31u << 11)) + 1u;
  bool fast;
  {
    unsigned int* xs = xcc_slots + g*32;
    if (tid == 0)
      __hip_atomic_store(&xs[nb], my_tag, __ATOMIC_RELAXED, __HIP_MEMORY_SCOPE_AGENT);
    unsigned long long bad;
    for (;;){
      unsigned int v = (lane < 32)
        ? __hip_atomic_load(&xs[lane], __ATOMIC_RELAXED, __HIP_MEMORY_SCOPE_AGENT)
        : my_tag;
      if (__ballot(v == 0u) == 0ull){ bad = __ballot(v != my_tag); break; }
      __builtin_amdgcn_s_sleep(1);
    }
    fast = (bad == 0ull);                // wave-uniform by construction
  }

  // B-fragments in registers: wave w -> matrix (w>>1), n-half (w&1)
  short8 bfrag[32];
  {
    int n = ((w >> 1) << 10) + j0 + ((w & 1) << 4) + col;
    const bf16* src = UrU + (size_t)n*1024 + (quad << 3);
    #pragma unroll
    for (int kt = 0; kt < 32; ++kt) bfrag[kt] = *(const short8*)(src + kt*32);
  }

  int r  = tid >> 4;                     // batch row 0..15
  int jp = (tid & 15) * 2;               // col pair
  float c0 = 0.f, c1 = 0.f;
  float2 brv = *(const float2*)(bias_r + j0 + jp);
  float2 bwv = *(const float2*)(bw     + j0 + jp);
  float2 buv = *(const float2*)(bu     + j0 + jp);

  for (int s = 0; s < 128; ++s){
    // prefetch P/G for this step (independent of the handshake)
    const bf16* Ps = P + (size_t)s*(128*2048) + (size_t)(b0 + r)*2048 + j0 + jp;
    unsigned int up1 = *(const unsigned int*)Ps;
    unsigned int up2 = *(const unsigned int*)(Ps + 1024);
    float gg = G[(b0 + r)*128 + s];

    // poll-the-data: this group's C = 16 x 512 tagged u64 = 4096 dwordx4.
    // Accept when every high word carries epoch s; detection returns the data.
    const uint4v* Cg = (const uint4v*)
      (Cpub + (size_t)(s & 1)*65536 + (size_t)b0*512);
    uint4v vv[16];
    unsigned int expct = (unsigned int)s;
    for (;;){
      if (fast){
        #pragma unroll
        for (int i = 0; i < 16; ++i) vv[i] = ld_l2_u128(Cg + tid + i*256);
      } else {
        #pragma unroll
        for (int i = 0; i < 16; ++i) vv[i] = ld_cg_u128(Cg + tid + i*256);
      }
      waitcnt_vm0();
      unsigned int bad = 0;
      #pragma unroll
      for (int i = 0; i < 16; ++i)
        bad |= (vv[i].y ^ expct) | (vv[i].w ^ expct);
      if (__ballot(bad != 0u) == 0ull) break;
      __builtin_amdgcn_s_sleep(1);
    }
    #pragma unroll
    for (int i = 0; i < 16; ++i){
      int p = tid + i*256;               // pair-of-u64 index 0..4095
      int rr = p >> 8, pi = p & 255;     // 256 pairs per batch row
      unsigned long long wdat = (unsigned long long)vv[i].x
                              | ((unsigned long long)vv[i].z << 32);
      *(unsigned long long*)&Cs[rr*CS + pi*4] = wdat;   // 4 bf16 cols
    }
    __syncthreads();                     // barrier #1: Cs ready

    // Q = C @ [Ur;U]^T (this block's 32 cols), two independent MFMA chains
    floatx4 a0 = (floatx4){0.f,0.f,0.f,0.f}, a1 = (floatx4){0.f,0.f,0.f,0.f};
    {
      const bf16* Ap = Cs + col*CS + (quad << 3);
      #pragma unroll
      for (int kt = 0; kt < 16; ++kt){
        short8 a = *(const short8*)(Ap + kt*32);
        a0 = __builtin_amdgcn_mfma_f32_16x16x32_bf16(a, bfrag[kt], a0, 0,0,0);
      }
      #pragma unroll
      for (int kt = 16; kt < 32; ++kt){
        short8 a = *(const short8*)(Ap + kt*32);
        a1 = __builtin_amdgcn_mfma_f32_16x16x32_bf16(a, bfrag[kt], a1, 0,0,0);
      }
    }
    {
      int mi = w >> 1, nh = w & 1;
      #pragma unroll
      for (int rr = 0; rr < 4; ++rr)
        Qex[mi*512 + (quad*4 + rr)*32 + nh*16 + col] = a0[rr] + a1[rr];
    }
    __syncthreads();                     // barrier #2: Qex ready

    // elementwise GRU-style update: thread owns (batch r, cols jp,jp+1)
    float p1a = __bfloat162float(*(const bf16*)&up1);
    float p1b = __bfloat162float(*((const bf16*)&up1 + 1));
    float p2a = __bfloat162float(*(const bf16*)&up2);
    float p2b = __bfloat162float(*((const bf16*)&up2 + 1));
    float2 q1 = *(const float2*)&Qex[r*32 + jp];
    float2 q2 = *(const float2*)&Qex[512 + r*32 + jp];
    float ra = sigm_f(p1a + q1.x + brv.x);
    float ha = tanh_f(p2a + bwv.x + ra*(q2.x + buv.x));
    c0 = gg*ha + (1.f - gg)*c0;
    float rb = sigm_f(p1b + q1.y + brv.y);
    float hb = tanh_f(p2b + bwv.y + rb*(q2.y + buv.y));
    c1 = gg*hb + (1.f - gg)*c1;

    // publish tagged {epoch=s+1, c0,c1}; no ack, no flag, no extra barrier.
    if (s != 127){
      union { bf16 h[2]; unsigned int u; } pk;
      pk.h[0] = __float2bfloat16(c0);
      pk.h[1] = __float2bfloat16(c1);
      unsigned long long wd = ((unsigned long long)(unsigned int)(s + 1) << 32)
                            | (unsigned long long)pk.u;
      unsigned long long* dst = Cpub + (size_t)((s & 1) ^ 1)*65536
                              + (size_t)(b0 + r)*512 + ((j0 + jp) >> 1);
      if (fast) st_l2_u64(dst, wd); else st_cg_u64(dst, wd);
    }
  }
  *(float2*)&Cfinal[(size_t)(b0 + r)*1024 + j0 + jp] = make_float2(c0, c1);
}

// ---------------- host launch ----------------
extern "C" void kernel_launch(void* const* d_in, const int* in_sizes, int n_in,
                              void* d_out, int out_size, void* d_ws, size_t ws_size,
                              hipStream_t stream) {
  const float* facts     = (const float*)d_in[0];
  const float* questions = (const float*)d_in[1];
  const float* prevM     = (const float*)d_in[2];
  const float* Wr        = (const float*)d_in[3];
  const float* br        = (const float*)d_in[4];
  const float* Ur        = (const float*)d_in[5];
  const float* bur       = (const float*)d_in[6];
  const float* Wf        = (const float*)d_in[7];
  const float* bw        = (const float*)d_in[8];
  const float* U         = (const float*)d_in[9];
  const float* bu        = (const float*)d_in[10];
  const float* Wz1       = (const float*)d_in[11];
  const float* bz1       = (const float*)d_in[12];
  const float* Wz2       = (const float*)d_in[13];
  const float* Wm        = (const float*)d_in[15];
  const float* bm        = (const float*)d_in[16];
  float* out = (float*)d_out;

  char* ws = (char*)d_ws;
  float*              score   = (float*)(ws + OFF_SCORE);
  unsigned int*       xccs    = (unsigned int*)(ws + OFF_XCC);
  unsigned long long* Cpub    = (unsigned long long*)(ws + OFF_CPUB);
  float*              G       = (float*)(ws + OFF_G);
  float*              bias_r  = (float*)(ws + OFF_BIASR);
  float*              Cfin    = (float*)(ws + OFF_CFIN);
  bf16*               concat  = (bf16*)(ws + OFF_CONCAT);
  bf16*               facts_b = (bf16*)(ws + OFF_FACTS);
  bf16*               Wz1_b   = (bf16*)(ws + OFF_WZ1);
  bf16*               WrW_b   = (bf16*)(ws + OFF_WRW);
  bf16*               UrU_b   = (bf16*)(ws + OFF_URU);
  bf16*               Wm_b    = (bf16*)(ws + OFF_WM);
  bf16*               P       = (bf16*)(ws + OFF_P);

  hipMemsetAsync(ws, 0, ZERO_BYTES, stream);   // score + xcc slots + Cpub buf0

  cast_f32_bf16<<<16384, 256, 0, stream>>>(facts, facts_b, 16777216);
  cast_f32_bf16<<< 4096, 256, 0, stream>>>(Wz1, Wz1_b, 4194304);
  cast_f32_bf16<<< 1024, 256, 0, stream>>>(Wr, WrW_b,           1048576);
  cast_f32_bf16<<< 1024, 256, 0, stream>>>(Wf, WrW_b + 1048576, 1048576);
  cast_f32_bf16<<< 1024, 256, 0, stream>>>(Ur, UrU_b,           1048576);
  cast_f32_bf16<<< 1024, 256, 0, stream>>>(U,  UrU_b + 1048576, 1048576);
  cast_f32_bf16<<< 3072, 256, 0, stream>>>(Wm, Wm_b, 3145728);
  add_bias_k<<<4, 256, 0, stream>>>(br, bur, bias_r);

  gate_gemm<<<dim3(8, 128), 256, 0, stream>>>(facts, questions, prevM, Wz1_b, bz1, Wz2, score);
  softmax128<<<128, 128, 0, stream>>>(score, G);

  gemm_bt<0><<<dim3(16, 128), 256, 0, stream>>>(facts_b, WrW_b, 1024, P, nullptr, nullptr);

  scan_kernel<<<256, 256, 0, stream>>>(UrU_b, P, G, bias_r, bw, bu, Cpub, Cfin, xccs);

  build_concat<<<384, 256, 0, stream>>>(prevM, Cfin, questions, concat);
  gemm_bt<1><<<dim3(8, 1), 256, 0, stream>>>(concat, Wm_b, 3072, nullptr, bm, out);
}

// Round 3
// 833.044 us; speedup vs baseline: 1.2382x; 1.2382x over previous
//
#include <hip/hip_runtime.h>
#include <hip/hip_bf16.h>

typedef __attribute__((ext_vector_type(8))) short short8;
typedef __attribute__((ext_vector_type(4))) short short4v;
typedef __attribute__((ext_vector_type(4))) float floatx4;
typedef __attribute__((ext_vector_type(4))) unsigned int uint4v;

using bf16 = __hip_bfloat16;

#define DEVI __device__ __forceinline__

// ---------------- workspace layout (bytes) ----------------
static constexpr size_t OFF_SCORE  = 0;                        // 128*128 f32
static constexpr size_t OFF_XCC    = 65536;                    // 8 groups * 32 slots u32 (+pad)
static constexpr size_t OFF_CPUB   = OFF_XCC + 4096;           // 2 x (128*512 u64) epoch-tagged C
static constexpr size_t ZERO_BYTES = OFF_CPUB + 524288;        // score + xcc + Cpub buf0 (epoch0 == C0=0)
static constexpr size_t OFF_G      = OFF_CPUB   + 1048576;     // 128*128 f32
static constexpr size_t OFF_BIASR  = OFF_G      + 65536;       // 1024 f32
static constexpr size_t OFF_CFIN   = OFF_BIASR  + 4096;        // 128*1024 f32
static constexpr size_t OFF_CONCAT = OFF_CFIN   + 524288;      // 128*3072 bf16
static constexpr size_t OFF_FACTS  = OFF_CONCAT + 786432;      // 16M bf16
static constexpr size_t OFF_WZ1    = OFF_FACTS  + 33554432ull; // 1024*4096 bf16
static constexpr size_t OFF_WRW    = OFF_WZ1    + 8388608ull;  // 2048*1024 bf16
static constexpr size_t OFF_URU    = OFF_WRW    + 4194304ull;  // 2048*1024 bf16
static constexpr size_t OFF_WM     = OFF_URU    + 4194304ull;  // 1024*3072 bf16
static constexpr size_t OFF_P      = OFF_WM     + 6291456ull;  // 128*128*2048 bf16

DEVI float sigm_f(float x){ return 1.f/(1.f + __expf(-x)); }
DEVI float tanh_f(float x){ float e = __expf(2.f*x); return 1.f - 2.f/(e + 1.f); }

// ---- coherence-tiered access helpers ----
DEVI uint4v ld_cg_u128(const uint4v* p){
  uint4v r;
  asm volatile("global_load_dwordx4 %0, %1, off sc0 sc1" : "=v"(r) : "v"(p) : "memory");
  return r;
}
DEVI uint4v ld_l2_u128(const uint4v* p){
  uint4v r;
  asm volatile("global_load_dwordx4 %0, %1, off sc0" : "=v"(r) : "v"(p) : "memory");
  return r;
}
DEVI void st_cg_u64(unsigned long long* p, unsigned long long v){
  asm volatile("global_store_dwordx2 %0, %1, off sc0 sc1" : : "v"(p), "v"(v) : "memory");
}
DEVI void st_l2_u64(unsigned long long* p, unsigned long long v){
  asm volatile("global_store_dwordx2 %0, %1, off" : : "v"(p), "v"(v) : "memory");
}
DEVI void waitcnt_vm0(){ asm volatile("s_waitcnt vmcnt(0)" ::: "memory"); }

// ---------------- small utility kernels ----------------
__global__ void cast_f32_bf16(const float* __restrict__ src, bf16* __restrict__ dst, int n){
  int i = (blockIdx.x*256 + threadIdx.x)*4;
  if (i >= n) return;
  float4 v = *(const float4*)(src + i);
  union { bf16 h[4]; short4v s; } u;
  u.h[0] = __float2bfloat16(v.x); u.h[1] = __float2bfloat16(v.y);
  u.h[2] = __float2bfloat16(v.z); u.h[3] = __float2bfloat16(v.w);
  *(short4v*)(dst + i) = u.s;
}

__global__ void add_bias_k(const float* __restrict__ a, const float* __restrict__ b, float* __restrict__ o){
  int i = blockIdx.x*256 + threadIdx.x;
  if (i < 1024) o[i] = a[i] + b[i];
}

__global__ void softmax128(const float* __restrict__ score, float* __restrict__ G){
  int b = blockIdx.x, t = threadIdx.x;
  int lane = t & 63, wv = t >> 6;
  float v = score[b*128 + t];
  float mx = v;
  #pragma unroll
  for (int m = 1; m < 64; m <<= 1) mx = fmaxf(mx, __shfl_xor(mx, m));
  __shared__ float r1[2], r2[2];
  if (lane == 0) r1[wv] = mx;
  __syncthreads();
  mx = fmaxf(r1[0], r1[1]);
  float e = __expf(v - mx);
  float sm = e;
  #pragma unroll
  for (int m = 1; m < 64; m <<= 1) sm += __shfl_xor(sm, m);
  if (lane == 0) r2[wv] = sm;
  __syncthreads();
  sm = r2[0] + r2[1];
  G[b*128 + t] = e / sm;
}

__global__ void build_concat(const float* __restrict__ prevM, const float* __restrict__ Cfin,
                             const float* __restrict__ q, bf16* __restrict__ out){
  int i = (blockIdx.x*256 + threadIdx.x)*4;   // n = 128*3072
  if (i >= 128*3072) return;
  int b = i / 3072, k = i % 3072;
  const float* src = (k < 1024) ? (prevM + b*1024 + k)
                   : (k < 2048) ? (Cfin + b*1024 + (k-1024))
                                : (q    + b*1024 + (k-2048));
  float4 v = *(const float4*)src;
  union { bf16 h[4]; short4v s; } u;
  u.h[0] = __float2bfloat16(v.x); u.h[1] = __float2bfloat16(v.y);
  u.h[2] = __float2bfloat16(v.z); u.h[3] = __float2bfloat16(v.w);
  *(short4v*)(out + i) = u.s;
}

// ---------------- gate GEMM: K-reordered so facts loads ONCE per 64-col chunk ----------------
// R7 change: outer loop over 16 facts chunks (held in registers, prefetched),
// inner loop over the 4 z-quadrants (f*q, f*m, |f-q|, |f-m|) accumulating into
// the same acc (K-order is irrelevant to the sum). Cuts facts global traffic 4x
// and removes the global-load wait from 3 of every 4 staging phases.
__global__ __launch_bounds__(256, 2) void gate_gemm(
    const float* __restrict__ facts, const float* __restrict__ q,
    const float* __restrict__ pm, const bf16* __restrict__ Wz1b,
    const float* __restrict__ bz1, const float* __restrict__ wz2,
    float* __restrict__ score)
{
  constexpr int TS = 80;
  __shared__ bf16 As[128*TS];
  __shared__ bf16 Bs[128*TS];
  __shared__ float qs[1024];
  __shared__ float ms[1024];
  int tid = threadIdx.x;
  int b  = blockIdx.y;
  int n0 = blockIdx.x * 128;
  int w = tid >> 6, lane = tid & 63;
  int wm = w >> 1, wn = w & 1;
  int quad = lane >> 4, col = lane & 15;

  for (int i = tid; i < 1024; i += 256){ qs[i] = q[b*1024 + i]; ms[i] = pm[b*1024 + i]; }
  __syncthreads();

  floatx4 acc[4][4];
  #pragma unroll
  for (int a = 0; a < 4; ++a)
    #pragma unroll
    for (int c = 0; c < 4; ++c) acc[a][c] = (floatx4){0.f,0.f,0.f,0.f};

  // staging geometry: thread handles column-octet cc (8 consecutive k),
  // rows r0, r0+32, r0+64, r0+96 (4 stages)
  int cc = tid & 7;
  int r0 = tid >> 3;

  float fc[4][8];   // current facts chunk (rows x 8 cols, f32)
  float fn[4][8];   // prefetched next chunk
  float q8[8], m8[8];

  // initial chunk load (kk0 = 0)
  #pragma unroll
  for (int i = 0; i < 4; ++i){
    const float* fp = facts + (size_t)(b*128 + r0 + i*32)*1024 + cc*8;
    *(float4*)(fc[i])   = *(const float4*)(fp);
    *(float4*)(fc[i]+4) = *(const float4*)(fp + 4);
  }

  for (int it = 0; it < 16; ++it){
    int kk0 = it * 64;
    int kk  = kk0 + cc*8;
    // aux values for this chunk (same 8 cols for all 4 row-stages)
    *(float4*)(q8)   = *(const float4*)(qs + kk);
    *(float4*)(q8+4) = *(const float4*)(qs + kk + 4);
    *(float4*)(m8)   = *(const float4*)(ms + kk);
    *(float4*)(m8+4) = *(const float4*)(ms + kk + 4);
    // prefetch next facts chunk (hidden under the 4 quadrant phases)
    if (it < 15){
      #pragma unroll
      for (int i = 0; i < 4; ++i){
        const float* fp = facts + (size_t)(b*128 + r0 + i*32)*1024 + kk0 + 64 + cc*8;
        *(float4*)(fn[i])   = *(const float4*)(fp);
        *(float4*)(fn[i]+4) = *(const float4*)(fp + 4);
      }
    }

    #pragma unroll
    for (int qd = 0; qd < 4; ++qd){
      // issue Bs loads first (latency overlaps the As build below)
      uint4v breg[4];
      #pragma unroll
      for (int i = 0; i < 4; ++i)
        breg[i] = *(const uint4v*)(Wz1b + (size_t)(n0 + r0 + i*32)*4096 + qd*1024 + kk);

      // build As from registers (no global traffic)
      #pragma unroll
      for (int i = 0; i < 4; ++i){
        union { bf16 h[8]; short8 s8; } u;
        if (qd == 0){
          #pragma unroll
          for (int j = 0; j < 8; ++j) u.h[j] = __float2bfloat16(fc[i][j]*q8[j]);
        } else if (qd == 1){
          #pragma unroll
          for (int j = 0; j < 8; ++j) u.h[j] = __float2bfloat16(fc[i][j]*m8[j]);
        } else if (qd == 2){
          #pragma unroll
          for (int j = 0; j < 8; ++j) u.h[j] = __float2bfloat16(fabsf(fc[i][j]-q8[j]));
        } else {
          #pragma unroll
          for (int j = 0; j < 8; ++j) u.h[j] = __float2bfloat16(fabsf(fc[i][j]-m8[j]));
        }
        *(short8*)&As[(r0 + i*32)*TS + cc*8] = u.s8;
        *(uint4v*)&Bs[(r0 + i*32)*TS + cc*8] = breg[i];
      }
      __syncthreads();   // staging done (prev MFMA phase was fenced by loop-end barrier)

      #pragma unroll
      for (int kt = 0; kt < 2; ++kt){
        short8 af[4], bfv[4];
        #pragma unroll
        for (int mt = 0; mt < 4; ++mt)
          af[mt] = *(const short8*)&As[(wm*64 + mt*16 + col)*TS + kt*32 + quad*8];
        #pragma unroll
        for (int nt = 0; nt < 4; ++nt)
          bfv[nt] = *(const short8*)&Bs[(wn*64 + nt*16 + col)*TS + kt*32 + quad*8];
        #pragma unroll
        for (int mt = 0; mt < 4; ++mt)
          #pragma unroll
          for (int nt = 0; nt < 4; ++nt)
            acc[mt][nt] = __builtin_amdgcn_mfma_f32_16x16x32_bf16(af[mt], bfv[nt], acc[mt][nt], 0,0,0);
      }
      __syncthreads();   // MFMA reads done; next staging may overwrite
    }

    // rotate prefetched chunk into place (pure register moves)
    if (it < 15){
      #pragma unroll
      for (int i = 0; i < 4; ++i)
        #pragma unroll
        for (int j = 0; j < 8; ++j) fc[i][j] = fn[i][j];
    }
  }

  #pragma unroll
  for (int mt = 0; mt < 4; ++mt){
    float part[4] = {0.f,0.f,0.f,0.f};
    #pragma unroll
    for (int nt = 0; nt < 4; ++nt){
      int n = n0 + wn*64 + nt*16 + col;
      float b1 = bz1[n], w2 = wz2[n];
      #pragma unroll
      for (int rr = 0; rr < 4; ++rr)
        part[rr] += tanh_f(acc[mt][nt][rr] + b1) * w2;
    }
    #pragma unroll
    for (int rr = 0; rr < 4; ++rr){
      float p = part[rr];
      p += __shfl_xor(p, 1); p += __shfl_xor(p, 2);
      p += __shfl_xor(p, 4); p += __shfl_xor(p, 8);
      if (col == 0)
        atomicAdd(&score[b*128 + wm*64 + mt*16 + quad*4 + rr], p);
    }
  }
}

// ---------------- generic 128x128 bf16 GEMM (B^T layout, R2-proven form) ----------------
template<int MODE>
__global__ __launch_bounds__(256, 2) void gemm_bt(
    const bf16* __restrict__ A, const bf16* __restrict__ Bm, int K,
    bf16* __restrict__ Pout, const float* __restrict__ bias, float* __restrict__ out)
{
  constexpr int TS = 80;
  __shared__ bf16 As[128*TS];
  __shared__ bf16 Bs[128*TS];
  int tid = threadIdx.x;
  int m0 = blockIdx.y * 128, n0 = blockIdx.x * 128;
  int w = tid >> 6, lane = tid & 63;
  int wm = w >> 1, wn = w & 1;
  int quad = lane >> 4, col = lane & 15;

  floatx4 acc[4][4];
  #pragma unroll
  for (int a = 0; a < 4; ++a)
    #pragma unroll
    for (int c = 0; c < 4; ++c) acc[a][c] = (floatx4){0.f,0.f,0.f,0.f};

  int nkb = K >> 6;
  for (int it = 0; it < nkb; ++it){
    int k0 = it * 64;
    #pragma unroll
    for (int i = 0; i < 4; ++i){
      int c = tid + i*256;
      int r = c >> 3, cc = c & 7;
      *(uint4v*)&As[r*TS + cc*8] = *(const uint4v*)(A  + (size_t)(m0 + r)*K + k0 + cc*8);
      *(uint4v*)&Bs[r*TS + cc*8] = *(const uint4v*)(Bm + (size_t)(n0 + r)*K + k0 + cc*8);
    }
    __syncthreads();
    #pragma unroll
    for (int kt = 0; kt < 2; ++kt){
      short8 af[4], bfv[4];
      #pragma unroll
      for (int mt = 0; mt < 4; ++mt)
        af[mt] = *(const short8*)&As[(wm*64 + mt*16 + col)*TS + kt*32 + quad*8];
      #pragma unroll
      for (int nt = 0; nt < 4; ++nt)
        bfv[nt] = *(const short8*)&Bs[(wn*64 + nt*16 + col)*TS + kt*32 + quad*8];
      #pragma unroll
      for (int mt = 0; mt < 4; ++mt)
        #pragma unroll
        for (int nt = 0; nt < 4; ++nt)
          acc[mt][nt] = __builtin_amdgcn_mfma_f32_16x16x32_bf16(af[mt], bfv[nt], acc[mt][nt], 0,0,0);
    }
    __syncthreads();
  }
  #pragma unroll
  for (int mt = 0; mt < 4; ++mt)
    #pragma unroll
    for (int nt = 0; nt < 4; ++nt)
      #pragma unroll
      for (int rr = 0; rr < 4; ++rr){
        int m = m0 + wm*64 + mt*16 + quad*4 + rr;
        int n = n0 + wn*64 + nt*16 + col;
        float v = acc[mt][nt][rr];
        if (MODE == 0){
          Pout[((size_t)(m & 127)*128 + (m >> 7))*2048 + n] = __float2bfloat16(v);
        } else {
          out[(size_t)m*1024 + n] = fmaxf(v + bias[n], 0.f);
        }
      }
}

// ---------------- the sequential scan ----------------
__global__ __launch_bounds__(256, 1) void scan_kernel(
    const bf16* __restrict__ UrU, const bf16* __restrict__ P,
    const float* __restrict__ G, const float* __restrict__ bias_r,
    const float* __restrict__ bw, const float* __restrict__ bu,
    unsigned long long* __restrict__ Cpub, float* __restrict__ Cfinal,
    unsigned int* __restrict__ xcc_slots)
{
  constexpr int CS = 1040;               // padded LDS stride (bf16), 16B-aligned
  __shared__ bf16 Cs[16*CS];
  __shared__ float Qex[2*16*32];         // [matrix][batch][col]
  int tid = threadIdx.x;
  int g  = blockIdx.x & 7;               // XCD-affine batch group 0..7
  int nb = blockIdx.x >> 3;              // column block 0..31
  int b0 = g * 16, j0 = nb * 32;
  int w = tid >> 6, lane = tid & 63;
  int quad = lane >> 4, col = lane & 15;

  // ---- one-time XCD discovery; all blocks co-resident (scan requires it) ----
  unsigned int my_tag = __builtin_amdgcn_s_getreg(20 | (31u << 11)) + 1u;
  bool fast;
  {
    unsigned int* xs = xcc_slots + g*32;
    if (tid == 0)
      __hip_atomic_store(&xs[nb], my_tag, __ATOMIC_RELAXED, __HIP_MEMORY_SCOPE_AGENT);
    unsigned long long bad;
    for (;;){
      unsigned int v = (lane < 32)
        ? __hip_atomic_load(&xs[lane], __ATOMIC_RELAXED, __HIP_MEMORY_SCOPE_AGENT)
        : my_tag;
      if (__ballot(v == 0u) == 0ull){ bad = __ballot(v != my_tag); break; }
      __builtin_amdgcn_s_sleep(1);
    }
    fast = (bad == 0ull);                // wave-uniform by construction
  }

  // B-fragments in registers: wave w -> matrix (w>>1), n-half (w&1)
  short8 bfrag[32];
  {
    int n = ((w >> 1) << 10) + j0 + ((w & 1) << 4) + col;
    const bf16* src = UrU + (size_t)n*1024 + (quad << 3);
    #pragma unroll
    for (int kt = 0; kt < 32; ++kt) bfrag[kt] = *(const short8*)(src + kt*32);
  }

  int r  = tid >> 4;                     // batch row 0..15
  int jp = (tid & 15) * 2;               // col pair
  float c0 = 0.f, c1 = 0.f;
  float2 brv = *(const float2*)(bias_r + j0 + jp);
  float2 bwv = *(const float2*)(bw     + j0 + jp);
  float2 buv = *(const float2*)(bu     + j0 + jp);

  for (int s = 0; s < 128; ++s){
    // prefetch P/G for this step (independent of the handshake)
    const bf16* Ps = P + (size_t)s*(128*2048) + (size_t)(b0 + r)*2048 + j0 + jp;
    unsigned int up1 = *(const unsigned int*)Ps;
    unsigned int up2 = *(const unsigned int*)(Ps + 1024);
    float gg = G[(b0 + r)*128 + s];

    // poll-the-data: this group's C = 16 x 512 tagged u64 = 4096 dwordx4.
    const uint4v* Cg = (const uint4v*)
      (Cpub + (size_t)(s & 1)*65536 + (size_t)b0*512);
    uint4v vv[16];
    unsigned int expct = (unsigned int)s;
    for (;;){
      if (fast){
        #pragma unroll
        for (int i = 0; i < 16; ++i) vv[i] = ld_l2_u128(Cg + tid + i*256);
      } else {
        #pragma unroll
        for (int i = 0; i < 16; ++i) vv[i] = ld_cg_u128(Cg + tid + i*256);
      }
      waitcnt_vm0();
      unsigned int bad = 0;
      #pragma unroll
      for (int i = 0; i < 16; ++i)
        bad |= (vv[i].y ^ expct) | (vv[i].w ^ expct);
      if (__ballot(bad != 0u) == 0ull) break;
      __builtin_amdgcn_s_sleep(1);
    }
    #pragma unroll
    for (int i = 0; i < 16; ++i){
      int p = tid + i*256;               // pair-of-u64 index 0..4095
      int rr = p >> 8, pi = p & 255;     // 256 pairs per batch row
      unsigned long long wdat = (unsigned long long)vv[i].x
                              | ((unsigned long long)vv[i].z << 32);
      *(unsigned long long*)&Cs[rr*CS + pi*4] = wdat;   // 4 bf16 cols
    }
    __syncthreads();                     // barrier #1: Cs ready

    // Q = C @ [Ur;U]^T (this block's 32 cols), two independent MFMA chains
    floatx4 a0 = (floatx4){0.f,0.f,0.f,0.f}, a1 = (floatx4){0.f,0.f,0.f,0.f};
    {
      const bf16* Ap = Cs + col*CS + (quad << 3);
      #pragma unroll
      for (int kt = 0; kt < 16; ++kt){
        short8 a = *(const short8*)(Ap + kt*32);
        a0 = __builtin_amdgcn_mfma_f32_16x16x32_bf16(a, bfrag[kt], a0, 0,0,0);
      }
      #pragma unroll
      for (int kt = 16; kt < 32; ++kt){
        short8 a = *(const short8*)(Ap + kt*32);
        a1 = __builtin_amdgcn_mfma_f32_16x16x32_bf16(a, bfrag[kt], a1, 0,0,0);
      }
    }
    {
      int mi = w >> 1, nh = w & 1;
      #pragma unroll
      for (int rr = 0; rr < 4; ++rr)
        Qex[mi*512 + (quad*4 + rr)*32 + nh*16 + col] = a0[rr] + a1[rr];
    }
    __syncthreads();                     // barrier #2: Qex ready

    // elementwise GRU-style update: thread owns (batch r, cols jp,jp+1)
    float p1a = __bfloat162float(*(const bf16*)&up1);
    float p1b = __bfloat162float(*((const bf16*)&up1 + 1));
    float p2a = __bfloat162float(*(const bf16*)&up2);
    float p2b = __bfloat162float(*((const bf16*)&up2 + 1));
    float2 q1 = *(const float2*)&Qex[r*32 + jp];
    float2 q2 = *(const float2*)&Qex[512 + r*32 + jp];
    float ra = sigm_f(p1a + q1.x + brv.x);
    float ha = tanh_f(p2a + bwv.x + ra*(q2.x + buv.x));
    c0 = gg*ha + (1.f - gg)*c0;
    float rb = sigm_f(p1b + q1.y + brv.y);
    float hb = tanh_f(p2b + bwv.y + rb*(q2.y + buv.y));
    c1 = gg*hb + (1.f - gg)*c1;

    // publish tagged {epoch=s+1, c0,c1}; no ack, no flag, no extra barrier.
    if (s != 127){
      union { bf16 h[2]; unsigned int u; } pk;
      pk.h[0] = __float2bfloat16(c0);
      pk.h[1] = __float2bfloat16(c1);
      unsigned long long wd = ((unsigned long long)(unsigned int)(s + 1) << 32)
                            | (unsigned long long)pk.u;
      unsigned long long* dst = Cpub + (size_t)((s & 1) ^ 1)*65536
                              + (size_t)(b0 + r)*512 + ((j0 + jp) >> 1);
      if (fast) st_l2_u64(dst, wd); else st_cg_u64(dst, wd);
    }
  }
  *(float2*)&Cfinal[(size_t)(b0 + r)*1024 + j0 + jp] = make_float2(c0, c1);
}

// ---------------- host launch ----------------
extern "C" void kernel_launch(void* const* d_in, const int* in_sizes, int n_in,
                              void* d_out, int out_size, void* d_ws, size_t ws_size,
                              hipStream_t stream) {
  const float* facts     = (const float*)d_in[0];
  const float* questions = (const float*)d_in[1];
  const float* prevM     = (const float*)d_in[2];
  const float* Wr        = (const float*)d_in[3];
  const float* br        = (const float*)d_in[4];
  const float* Ur        = (const float*)d_in[5];
  const float* bur       = (const float*)d_in[6];
  const float* Wf        = (const float*)d_in[7];
  const float* bw        = (const float*)d_in[8];
  const float* U         = (const float*)d_in[9];
  const float* bu        = (const float*)d_in[10];
  const float* Wz1       = (const float*)d_in[11];
  const float* bz1       = (const float*)d_in[12];
  const float* Wz2       = (const float*)d_in[13];
  const float* Wm        = (const float*)d_in[15];
  const float* bm        = (const float*)d_in[16];
  float* out = (float*)d_out;

  char* ws = (char*)d_ws;
  float*              score   = (float*)(ws + OFF_SCORE);
  unsigned int*       xccs    = (unsigned int*)(ws + OFF_XCC);
  unsigned long long* Cpub    = (unsigned long long*)(ws + OFF_CPUB);
  float*              G       = (float*)(ws + OFF_G);
  float*              bias_r  = (float*)(ws + OFF_BIASR);
  float*              Cfin    = (float*)(ws + OFF_CFIN);
  bf16*               concat  = (bf16*)(ws + OFF_CONCAT);
  bf16*               facts_b = (bf16*)(ws + OFF_FACTS);
  bf16*               Wz1_b   = (bf16*)(ws + OFF_WZ1);
  bf16*               WrW_b   = (bf16*)(ws + OFF_WRW);
  bf16*               UrU_b   = (bf16*)(ws + OFF_URU);
  bf16*               Wm_b    = (bf16*)(ws + OFF_WM);
  bf16*               P       = (bf16*)(ws + OFF_P);

  hipMemsetAsync(ws, 0, ZERO_BYTES, stream);   // score + xcc slots + Cpub buf0

  cast_f32_bf16<<<16384, 256, 0, stream>>>(facts, facts_b, 16777216);
  cast_f32_bf16<<< 4096, 256, 0, stream>>>(Wz1, Wz1_b, 4194304);
  cast_f32_bf16<<< 1024, 256, 0, stream>>>(Wr, WrW_b,           1048576);
  cast_f32_bf16<<< 1024, 256, 0, stream>>>(Wf, WrW_b + 1048576, 1048576);
  cast_f32_bf16<<< 1024, 256, 0, stream>>>(Ur, UrU_b,           1048576);
  cast_f32_bf16<<< 1024, 256, 0, stream>>>(U,  UrU_b + 1048576, 1048576);
  cast_f32_bf16<<< 3072, 256, 0, stream>>>(Wm, Wm_b, 3145728);
  add_bias_k<<<4, 256, 0, stream>>>(br, bur, bias_r);

  gate_gemm<<<dim3(8, 128), 256, 0, stream>>>(facts, questions, prevM, Wz1_b, bz1, Wz2, score);
  softmax128<<<128, 128, 0, stream>>>(score, G);

  gemm_bt<0><<<dim3(16, 128), 256, 0, stream>>>(facts_b, WrW_b, 1024, P, nullptr, nullptr);

  scan_kernel<<<256, 256, 0, stream>>>(UrU_b, P, G, bias_r, bw, bu, Cpub, Cfin, xccs);

  build_concat<<<384, 256, 0, stream>>>(prevM, Cfin, questions, concat);
  gemm_bt<1><<<dim3(8, 1), 256, 0, stream>>>(concat, Wm_b, 3072, nullptr, bm, out);
}